// Round 13
// baseline (202.817 us; speedup 1.0000x reference)
//
#include <hip/hip_runtime.h>
#include <hip/hip_bf16.h>
#include <cstddef>
#include <cstdint>

#define D_MODEL 256
#define N_TOK   16384
#define NHEAD   8
#define HDIM    32
#define LNEIGH  32
#define DFF     2048
#define HCP     2080   // padded pitch for hc / W2T (breaks 4KB stride)

typedef short bf16x8 __attribute__((ext_vector_type(8)));
typedef float f32x4  __attribute__((ext_vector_type(4)));

__device__ __forceinline__ float b2f(short s) {
    unsigned u = ((unsigned)(unsigned short)s) << 16;
    return __builtin_bit_cast(float, u);
}

// global -> LDS async copy, 16B per lane; LDS fills base + lane*16.
__device__ __forceinline__ void gload_lds16(const void* g, void* l) {
    auto* gp = reinterpret_cast<const __attribute__((address_space(1))) uint32_t*>(
        reinterpret_cast<uintptr_t>(g));
    auto* lp = reinterpret_cast<__attribute__((address_space(3))) uint32_t*>(
        reinterpret_cast<uintptr_t>(l));
    __builtin_amdgcn_global_load_lds(gp, lp, 16, 0, 0);
}

// ---------------------------------------------------------------------------
// bf16 MFMA GEMM, 128x128 tile, 4 waves, double-buffered K-loop.
// C = A[M,K] @ Bt[N,K]^T. Epilogue: +bias, relu, bf16 out (pitch ldc).
// Used for FFN1 (grid (16,128) = 2048 blocks, 8/CU -> ~690 TF).
// ---------------------------------------------------------------------------
__global__ __launch_bounds__(256) void gemm_bt(
    const __hip_bfloat16* __restrict__ A, int lda,
    const __hip_bfloat16* __restrict__ Bt, int ldb,
    const float* __restrict__ bias,
    __hip_bfloat16* __restrict__ outb, int ldc,
    int M, int N, int K, int relu)
{
    __shared__ short Asm[2][128 * 32];
    __shared__ short Bsm[2][128 * 32];

    const int tid  = threadIdx.x;
    const int lane = tid & 63;
    const int wid  = tid >> 6;
    const int wr   = wid >> 1;
    const int wc   = wid & 1;
    const int bm   = blockIdx.y * 128;
    const int bn   = blockIdx.x * 128;

    f32x4 acc[4][4] = {};
    const int srow = lane >> 2;
    const int seg  = (lane & 3) * 8;

    auto stage = [&](int buf, int k0) {
        #pragma unroll
        for (int t = 0; t < 2; ++t) {
            int rbase = wid * 32 + t * 16;
            gload_lds16(A  + (size_t)(bm + rbase + srow) * lda + k0 + seg, &Asm[buf][rbase * 32]);
            gload_lds16(Bt + (size_t)(bn + rbase + srow) * ldb + k0 + seg, &Bsm[buf][rbase * 32]);
        }
    };

    const int nk = K >> 5;
    stage(0, 0);
    __syncthreads();

    for (int kk = 0; kk < nk; ++kk) {
        const int cur = kk & 1;
        if (kk + 1 < nk) stage(cur ^ 1, (kk + 1) << 5);

        bf16x8 a[4], b[4];
        #pragma unroll
        for (int i = 0; i < 4; ++i)
            a[i] = *(const bf16x8*)&Asm[cur][(wr * 64 + i * 16 + (lane & 15)) * 32 + (lane >> 4) * 8];
        #pragma unroll
        for (int j = 0; j < 4; ++j)
            b[j] = *(const bf16x8*)&Bsm[cur][(wc * 64 + j * 16 + (lane & 15)) * 32 + (lane >> 4) * 8];
        #pragma unroll
        for (int i = 0; i < 4; ++i)
            #pragma unroll
            for (int j = 0; j < 4; ++j)
                acc[i][j] = __builtin_amdgcn_mfma_f32_16x16x32_bf16(a[i], b[j], acc[i][j], 0, 0, 0);
        __syncthreads();
    }

    #pragma unroll
    for (int i = 0; i < 4; ++i) {
        int rbase = bm + wr * 64 + i * 16 + ((lane >> 4) << 2);
        #pragma unroll
        for (int j = 0; j < 4; ++j) {
            int col = bn + wc * 64 + j * 16 + (lane & 15);
            float bval = bias ? bias[col] : 0.0f;
            #pragma unroll
            for (int r = 0; r < 4; ++r) {
                int row = rbase + r;
                float v = acc[i][j][r] + bval;
                if (relu) v = fmaxf(v, 0.0f);
                outb[(size_t)row * ldc + col] = __float2bfloat16(v);
            }
        }
    }
}

// ---------------------------------------------------------------------------
// NO-LDS GEMM + fused bias/residual/LayerNorm. BM=64 x N=256, 8 waves (2x4),
// wave = 32x64 (acc 2x4). A-frags come straight from global (shared by the 4
// column-waves -> L1 broadcast); B-frags straight from global (weight is
// L2-resident). ZERO barriers in the K-loop -> no vmcnt(0) drain; the
// compiler software-pipelines the 6 loads per 8 MFMA (round-11's failure was
// the per-step __syncthreads, not the global loads). LDS only for LN reduce.
// ---------------------------------------------------------------------------
__global__ __launch_bounds__(512) void gemm_nolds_ln(
    const __hip_bfloat16* __restrict__ A, int lda,
    const __hip_bfloat16* __restrict__ Bt, int ldb,
    const float* __restrict__ bias,
    const float* __restrict__ residf,
    const __hip_bfloat16* __restrict__ residb,
    const float* __restrict__ g,
    const float* __restrict__ be,
    float* __restrict__ outf,
    __hip_bfloat16* __restrict__ outb,
    int K)
{
    __shared__ float lnS[8][64], lnS2[8][64];
    __shared__ float rmu[64], rrs[64];

    const int tid  = threadIdx.x;
    const int lane = tid & 63;
    const int wid  = tid >> 6;           // 0..7
    const int wr   = wid >> 2;           // 0..1 (32-row half)
    const int wc   = wid & 3;            // 0..3 (64-col quarter)
    const int bm   = blockIdx.x * 64;
    const int lo   = lane & 15;
    const int hi   = lane >> 4;

    f32x4 acc[2][4] = {};

    // per-lane row base pointers (fragment layout: row=+lo, chunk=hi)
    const __hip_bfloat16* arow0 = A + (size_t)(bm + wr * 32 + lo) * lda + hi * 8;
    const __hip_bfloat16* arow1 = arow0 + (size_t)16 * lda;
    const __hip_bfloat16* brow[4];
    #pragma unroll
    for (int j = 0; j < 4; ++j)
        brow[j] = Bt + (size_t)(wc * 64 + j * 16 + lo) * ldb + hi * 8;

    const int nk = K >> 5;
    #pragma unroll 2
    for (int kk = 0; kk < nk; ++kk) {
        const int ko = kk * 32;
        bf16x8 a0 = *(const bf16x8*)(arow0 + ko);
        bf16x8 a1 = *(const bf16x8*)(arow1 + ko);
        bf16x8 b0 = *(const bf16x8*)(brow[0] + ko);
        bf16x8 b1 = *(const bf16x8*)(brow[1] + ko);
        bf16x8 b2 = *(const bf16x8*)(brow[2] + ko);
        bf16x8 b3 = *(const bf16x8*)(brow[3] + ko);
        acc[0][0] = __builtin_amdgcn_mfma_f32_16x16x32_bf16(a0, b0, acc[0][0], 0, 0, 0);
        acc[0][1] = __builtin_amdgcn_mfma_f32_16x16x32_bf16(a0, b1, acc[0][1], 0, 0, 0);
        acc[0][2] = __builtin_amdgcn_mfma_f32_16x16x32_bf16(a0, b2, acc[0][2], 0, 0, 0);
        acc[0][3] = __builtin_amdgcn_mfma_f32_16x16x32_bf16(a0, b3, acc[0][3], 0, 0, 0);
        acc[1][0] = __builtin_amdgcn_mfma_f32_16x16x32_bf16(a1, b0, acc[1][0], 0, 0, 0);
        acc[1][1] = __builtin_amdgcn_mfma_f32_16x16x32_bf16(a1, b1, acc[1][1], 0, 0, 0);
        acc[1][2] = __builtin_amdgcn_mfma_f32_16x16x32_bf16(a1, b2, acc[1][2], 0, 0, 0);
        acc[1][3] = __builtin_amdgcn_mfma_f32_16x16x32_bf16(a1, b3, acc[1][3], 0, 0, 0);
    }

    // epilogue: bias + resid, per-row mean/var partials over this wave's 64 cols
    float ps[2][4] = {}, ps2[2][4] = {};
    #pragma unroll
    for (int j = 0; j < 4; ++j) {
        int col = wc * 64 + j * 16 + lo;
        float bval = bias ? bias[col] : 0.0f;
        #pragma unroll
        for (int i = 0; i < 2; ++i) {
            #pragma unroll
            for (int r = 0; r < 4; ++r) {
                int row = bm + wr * 32 + i * 16 + hi * 4 + r;
                float v = acc[i][j][r] + bval;
                size_t o = (size_t)row * 256 + col;
                if (residf) v += residf[o];
                if (residb) v += __bfloat162float(residb[o]);
                acc[i][j][r] = v;
                ps[i][r]  += v;
                ps2[i][r] += v * v;
            }
        }
    }
    #pragma unroll
    for (int i = 0; i < 2; ++i)
        #pragma unroll
        for (int r = 0; r < 4; ++r) {
            #pragma unroll
            for (int m = 1; m < 16; m <<= 1) {
                ps[i][r]  += __shfl_xor(ps[i][r],  m);
                ps2[i][r] += __shfl_xor(ps2[i][r], m);
            }
        }
    if (lo == 0) {
        #pragma unroll
        for (int i = 0; i < 2; ++i)
            #pragma unroll
            for (int r = 0; r < 4; ++r) {
                int rl = wr * 32 + i * 16 + hi * 4 + r;
                lnS[wid][rl]  = ps[i][r];
                lnS2[wid][rl] = ps2[i][r];
            }
    }
    __syncthreads();
    if (tid < 64) {
        int base = (tid >> 5) * 4;       // the 4 waves (wc=0..3) sharing this row
        float s  = lnS[base][tid] + lnS[base + 1][tid] + lnS[base + 2][tid] + lnS[base + 3][tid];
        float s2 = lnS2[base][tid] + lnS2[base + 1][tid] + lnS2[base + 2][tid] + lnS2[base + 3][tid];
        float mu  = s * (1.0f / 256.0f);
        float var = s2 * (1.0f / 256.0f) - mu * mu;
        rmu[tid] = mu;
        rrs[tid] = rsqrtf(var + 1e-5f);
    }
    __syncthreads();

    #pragma unroll
    for (int j = 0; j < 4; ++j) {
        int col = wc * 64 + j * 16 + lo;
        float gg = g[col], bb = be[col];
        #pragma unroll
        for (int i = 0; i < 2; ++i) {
            #pragma unroll
            for (int r = 0; r < 4; ++r) {
                int rl = wr * 32 + i * 16 + hi * 4 + r;
                float v = (acc[i][j][r] - rmu[rl]) * rrs[rl] * gg + bb;
                size_t o = (size_t)(bm + rl) * 256 + col;
                if (outf) outf[o] = v;
                if (outb) outb[o] = __float2bfloat16(v);
            }
        }
    }
}

// ---------------------------------------------------------------------------
// QKV GEMM: C = src_bf @ WqkvT^T (N=768, K=256), split epilogue:
// cols [0,256)  -> qf  f32 [N_TOK][256]   (scale pre-folded)
// cols [256,768)-> kvb bf16 [N_TOK][512]  (k|v, gather-friendly, L2-resident)
// ---------------------------------------------------------------------------
__global__ __launch_bounds__(256) void gemm_qkv(
    const __hip_bfloat16* __restrict__ A,
    const __hip_bfloat16* __restrict__ Bt,
    const float* __restrict__ bias,
    float* __restrict__ qf,
    __hip_bfloat16* __restrict__ kvb)
{
    __shared__ short Asm[2][128 * 32];
    __shared__ short Bsm[2][128 * 32];

    const int tid  = threadIdx.x;
    const int lane = tid & 63;
    const int wid  = tid >> 6;
    const int wr   = wid >> 1;
    const int wc   = wid & 1;
    const int bm   = blockIdx.y * 128;
    const int bn   = blockIdx.x * 128;

    f32x4 acc[4][4] = {};
    const int srow = lane >> 2;
    const int seg  = (lane & 3) * 8;

    auto stage = [&](int buf, int k0) {
        #pragma unroll
        for (int t = 0; t < 2; ++t) {
            int rbase = wid * 32 + t * 16;
            gload_lds16(A  + (size_t)(bm + rbase + srow) * 256 + k0 + seg, &Asm[buf][rbase * 32]);
            gload_lds16(Bt + (size_t)(bn + rbase + srow) * 256 + k0 + seg, &Bsm[buf][rbase * 32]);
        }
    };

    stage(0, 0);
    __syncthreads();
    for (int kk = 0; kk < 8; ++kk) {
        const int cur = kk & 1;
        if (kk + 1 < 8) stage(cur ^ 1, (kk + 1) << 5);
        bf16x8 a[4], b[4];
        #pragma unroll
        for (int i = 0; i < 4; ++i)
            a[i] = *(const bf16x8*)&Asm[cur][(wr * 64 + i * 16 + (lane & 15)) * 32 + (lane >> 4) * 8];
        #pragma unroll
        for (int j = 0; j < 4; ++j)
            b[j] = *(const bf16x8*)&Bsm[cur][(wc * 64 + j * 16 + (lane & 15)) * 32 + (lane >> 4) * 8];
        #pragma unroll
        for (int i = 0; i < 4; ++i)
            #pragma unroll
            for (int j = 0; j < 4; ++j)
                acc[i][j] = __builtin_amdgcn_mfma_f32_16x16x32_bf16(a[i], b[j], acc[i][j], 0, 0, 0);
        __syncthreads();
    }

    const bool isq = (bn < 256);
    #pragma unroll
    for (int i = 0; i < 4; ++i) {
        int rbase = bm + wr * 64 + i * 16 + ((lane >> 4) << 2);
        #pragma unroll
        for (int j = 0; j < 4; ++j) {
            int col = bn + wc * 64 + j * 16 + (lane & 15);
            float bval = bias[col];
            #pragma unroll
            for (int r = 0; r < 4; ++r) {
                int row = rbase + r;
                float v = acc[i][j][r] + bval;
                if (isq) qf[(size_t)row * 256 + col] = v;
                else     kvb[(size_t)row * 512 + (col - 256)] = __float2bfloat16(v);
            }
        }
    }
}

// ---------------------------------------------------------------------------
__global__ __launch_bounds__(256) void cvt_f2b(
    const float* __restrict__ x, __hip_bfloat16* __restrict__ y, int n)
{
    int i = (blockIdx.x * 256 + threadIdx.x) * 4;
    if (i >= n) return;
    float4 v = *(const float4*)(x + i);
    y[i + 0] = __float2bfloat16(v.x);
    y[i + 1] = __float2bfloat16(v.y);
    y[i + 2] = __float2bfloat16(v.z);
    y[i + 3] = __float2bfloat16(v.w);
}

// Tiled transpose: W[K][N] fp32 -> Wt[N][K] bf16, output pitch ldo.
__global__ __launch_bounds__(256) void cvt_wt_tiled(
    const float* __restrict__ W, __hip_bfloat16* __restrict__ Wt,
    int K, int N, int ldo, float scale)
{
    __shared__ float t[32][33];
    const int n0 = blockIdx.x * 32;
    const int k0 = blockIdx.y * 32;
    const int tx = threadIdx.x & 31;
    const int ty = threadIdx.x >> 5;
    #pragma unroll
    for (int i = 0; i < 32; i += 8)
        t[ty + i][tx] = W[(size_t)(k0 + ty + i) * N + n0 + tx];
    __syncthreads();
    #pragma unroll
    for (int i = 0; i < 32; i += 8)
        Wt[(size_t)(n0 + ty + i) * ldo + k0 + tx] = __float2bfloat16(t[tx][ty + i] * scale);
}

__global__ __launch_bounds__(256) void cvt_w3_tiled(
    const float* __restrict__ Wa, const float* __restrict__ Wb,
    const float* __restrict__ Wc, __hip_bfloat16* __restrict__ Wt,
    float scale_a)
{
    __shared__ float t[32][33];
    const int n0 = blockIdx.x * 32;
    const int k0 = blockIdx.y * 32;
    const float* W = (n0 < 256) ? Wa : (n0 < 512 ? Wb : Wc);
    const float sc = (n0 < 256) ? scale_a : 1.0f;
    const int ncol = n0 & 255;
    const int tx = threadIdx.x & 31;
    const int ty = threadIdx.x >> 5;
    #pragma unroll
    for (int i = 0; i < 32; i += 8)
        t[ty + i][tx] = W[(size_t)(k0 + ty + i) * 256 + ncol + tx];
    __syncthreads();
    #pragma unroll
    for (int i = 0; i < 32; i += 8)
        Wt[(size_t)(n0 + ty + i) * 256 + k0 + tx] = __float2bfloat16(t[tx][ty + i] * sc);
}

// biases + key_start prefix sums (batch offsets)
__global__ __launch_bounds__(768) void make_bqkv(
    const float* __restrict__ bq, const float* __restrict__ bk,
    const float* __restrict__ bv, const int* __restrict__ kbc, int nb,
    float* __restrict__ o, int* __restrict__ ks, float qs)
{
    int i = threadIdx.x;
    if (i < 256)      o[i] = bq[i] * qs;
    else if (i < 512) o[i] = bk[i - 256];
    else              o[i] = bv[i - 512];
    if (i < nb) {
        int acc = 0;
        for (int j = 0; j < i; ++j) acc += kbc[j];
        ks[i] = acc;
    }
}

// ---------------------------------------------------------------------------
// Gathered local attention: ONE WAVE per query, fully coalesced row gathers.
// (unchanged from round 9 — 210->169 us win)
// ---------------------------------------------------------------------------
__global__ __launch_bounds__(256) void attn_wave(
    const float* __restrict__ qf,
    const __hip_bfloat16* __restrict__ kvb,
    const int* __restrict__ index_pair,
    const int* __restrict__ ipb,
    const int* __restrict__ key_start,
    __hip_bfloat16* __restrict__ out)
{
    const int w    = threadIdx.x >> 6;
    const int lane = threadIdx.x & 63;
    const int bid  = blockIdx.x;
    const int n  = (bid & 7) * 2048 + (bid >> 3) * 4 + w;
    const int c  = lane & 31;      // dim chunk: dims [c*8, c*8+8)
    const int pp = lane >> 5;      // row parity

    int raw = index_pair[(size_t)n * LNEIGH + c];
    int ks  = key_start[ipb[n]];
    int gi0 = (raw >= 0) ? raw + ks : -1;

    const float* qp = qf + (size_t)n * 256 + c * 8;
    float4 q0 = *(const float4*)(qp);
    float4 q1 = *(const float4*)(qp + 4);

    int gi[16];
    #pragma unroll
    for (int i = 0; i < 16; ++i) gi[i] = __shfl(gi0, 2 * i + pp);

    bf16x8 kr[16];
    #pragma unroll
    for (int i = 0; i < 16; ++i) {
        int g = gi[i] < 0 ? 0 : gi[i];
        kr[i] = *(const bf16x8*)(kvb + (size_t)g * 512 + c * 8);
    }

    float s[16];
    #pragma unroll
    for (int i = 0; i < 16; ++i) {
        float t = q0.x * b2f(kr[i][0]) + q0.y * b2f(kr[i][1])
                + q0.z * b2f(kr[i][2]) + q0.w * b2f(kr[i][3])
                + q1.x * b2f(kr[i][4]) + q1.y * b2f(kr[i][5])
                + q1.z * b2f(kr[i][6]) + q1.w * b2f(kr[i][7]);
        t += __shfl_xor(t, 1);
        t += __shfl_xor(t, 2);
        s[i] = (gi[i] < 0) ? -1e9f : t;
    }

    bf16x8 vr[16];
    #pragma unroll
    for (int i = 0; i < 16; ++i) {
        int g = gi[i] < 0 ? 0 : gi[i];
        vr[i] = *(const bf16x8*)(kvb + (size_t)g * 512 + 256 + c * 8);
    }

    float m = s[0];
    #pragma unroll
    for (int i = 1; i < 16; ++i) m = fmaxf(m, s[i]);
    m = fmaxf(m, __shfl_xor(m, 32));
    float tot = 0.0f;
    #pragma unroll
    for (int i = 0; i < 16; ++i) { s[i] = __expf(s[i] - m); tot += s[i]; }
    tot += __shfl_xor(tot, 32);
    const float inv = 1.0f / tot;

    float a[8] = {};
    #pragma unroll
    for (int i = 0; i < 16; ++i) {
        float wt = s[i] * inv;
        #pragma unroll
        for (int j = 0; j < 8; ++j) a[j] += wt * b2f(vr[i][j]);
    }
    #pragma unroll
    for (int j = 0; j < 8; ++j) a[j] += __shfl_xor(a[j], 32);

    if (pp == 0) {
        bf16x8 ov;
        #pragma unroll
        for (int j = 0; j < 8; ++j)
            ov[j] = __builtin_bit_cast(short, __float2bfloat16(a[j]));
        *(bf16x8*)((short*)out + (size_t)n * 256 + c * 8) = ov;
    }
}

// ---------------------------------------------------------------------------
extern "C" void kernel_launch(void* const* d_in, const int* in_sizes, int n_in,
                              void* d_out, int out_size, void* d_ws, size_t ws_size,
                              hipStream_t stream)
{
    const float* src = (const float*)d_in[0];
    const int*   index_pair = (const int*)d_in[1];
    const int*   kbc = (const int*)d_in[3];
    const int*   ipb = (const int*)d_in[4];
    const float* Wq = (const float*)d_in[5];
    const float* bq = (const float*)d_in[6];
    const float* Wk = (const float*)d_in[7];
    const float* bk = (const float*)d_in[8];
    const float* Wv = (const float*)d_in[9];
    const float* bv = (const float*)d_in[10];
    const float* Wo = (const float*)d_in[11];
    const float* bo = (const float*)d_in[12];
    const float* W1 = (const float*)d_in[13];
    const float* b1 = (const float*)d_in[14];
    const float* W2 = (const float*)d_in[15];
    const float* b2 = (const float*)d_in[16];
    const float* g1 = (const float*)d_in[17];
    const float* be1 = (const float*)d_in[18];
    const float* g2 = (const float*)d_in[19];
    const float* be2 = (const float*)d_in[20];
    float* out = (float*)d_out;
    const int nb = in_sizes[3];   // number of batches

    char* ws = (char*)d_ws;
    // hc (68.2 MB, pitch 2080) aliases the attention-phase buffers (all dead
    // before FFN1 writes).
    const size_t O_HC    = 0;                        // 68.2 MB bf16 hidden
    const size_t O_SRCBF = 0;                        //  8.39 MB bf16 src
    const size_t O_QF    = 8388608;                  // 16.78 MB f32 q
    const size_t O_KVB   = 25165824;                 // 16.78 MB bf16 k|v
    const size_t O_ATTN  = 41943040;                 //  8.39 MB bf16 attn out
    const size_t O_XBF   = 68157440;                 //  8.39 MB bf16 x (LN1 out)
    const size_t O_WQKV  = 76546048;
    const size_t O_WO    = O_WQKV + 768 * 256 * 2;
    const size_t O_W1    = O_WO + 256 * 256 * 2;
    const size_t O_W2    = O_W1 + (size_t)DFF * 256 * 2;
    const size_t O_BQKV  = O_W2 + (size_t)256 * HCP * 2;
    const size_t O_KS    = O_BQKV + 4096;

    __hip_bfloat16* src_bf  = (__hip_bfloat16*)(ws + O_SRCBF);
    float*          qf      = (float*)(ws + O_QF);
    __hip_bfloat16* kvb     = (__hip_bfloat16*)(ws + O_KVB);
    __hip_bfloat16* attn_bf = (__hip_bfloat16*)(ws + O_ATTN);
    __hip_bfloat16* hc      = (__hip_bfloat16*)(ws + O_HC);
    __hip_bfloat16* x_bf    = (__hip_bfloat16*)(ws + O_XBF);
    __hip_bfloat16* WqkvT   = (__hip_bfloat16*)(ws + O_WQKV);
    __hip_bfloat16* WoT     = (__hip_bfloat16*)(ws + O_WO);
    __hip_bfloat16* W1T     = (__hip_bfloat16*)(ws + O_W1);
    __hip_bfloat16* W2T     = (__hip_bfloat16*)(ws + O_W2);
    float*          bqkv    = (float*)(ws + O_BQKV);
    int*            ksbuf   = (int*)(ws + O_KS);

    const dim3 blk(256);
    const float qscale = 0.17677669529663687f;

    // --- conversions ---
    cvt_f2b<<<N_TOK * D_MODEL / 4 / 256, blk, 0, stream>>>(src, src_bf, N_TOK * D_MODEL);
    cvt_w3_tiled<<<dim3(24, 8), blk, 0, stream>>>(Wq, Wk, Wv, WqkvT, qscale);
    cvt_wt_tiled<<<dim3(8, 8),  blk, 0, stream>>>(Wo, WoT, 256, 256, 256, 1.0f);
    cvt_wt_tiled<<<dim3(64, 8), blk, 0, stream>>>(W1, W1T, 256, DFF, 256, 1.0f);
    cvt_wt_tiled<<<dim3(8, 64), blk, 0, stream>>>(W2, W2T, DFF, 256, HCP, 1.0f);
    make_bqkv<<<1, 768, 0, stream>>>(bq, bk, bv, kbc, nb, bqkv, ksbuf, qscale);

    // --- fused QKV projection: q -> f32 qf, k|v -> bf16 kvb ---
    gemm_qkv<<<dim3(6, 128), blk, 0, stream>>>(src_bf, WqkvT, bqkv, qf, kvb);

    // --- gathered attention (wave per query, coalesced row gathers) ---
    attn_wave<<<dim3(N_TOK / 4), blk, 0, stream>>>(qf, kvb, index_pair, ipb, ksbuf, attn_bf);

    // --- Wo + residual(src) + LN1 fused -> x_bf (no-LDS GEMM) ---
    gemm_nolds_ln<<<dim3(N_TOK / 64), dim3(512), 0, stream>>>(
        attn_bf, 256, WoT, 256, bo, src, nullptr, g1, be1,
        nullptr, x_bf, 256);

    // --- FFN1 (N=2048, relu) -> hc (pitch 2080) ---
    gemm_bt<<<dim3(16, 128), blk, 0, stream>>>(
        x_bf, 256, W1T, 256, b1, hc, HCP, N_TOK, DFF, 256, 1);

    // --- FFN2 + residual(x_bf) + LN2 fused -> out (no-LDS GEMM) ---
    gemm_nolds_ln<<<dim3(N_TOK / 64), dim3(512), 0, stream>>>(
        hc, HCP, W2T, HCP, b2, nullptr, x_bf, g2, be2,
        out, nullptr, DFF);
}

// Round 14
// 159.908 us; speedup vs baseline: 1.2683x; 1.2683x over previous
//
#include <hip/hip_runtime.h>
#include <hip/hip_bf16.h>
#include <cstddef>
#include <cstdint>

#define D_MODEL 256
#define N_TOK   16384
#define NHEAD   8
#define HDIM    32
#define LNEIGH  32
#define DFF     2048

// dynamic LDS for gemm_bk64_ln: A dbuf 16K + B dbuf 64K + LN scratch
#define SMEM_LN (16384 + 65536 + 2048 + 2048 + 256 + 256)   // 86528 B

typedef short bf16x8 __attribute__((ext_vector_type(8)));
typedef float f32x4  __attribute__((ext_vector_type(4)));

__device__ __forceinline__ float b2f(short s) {
    unsigned u = ((unsigned)(unsigned short)s) << 16;
    return __builtin_bit_cast(float, u);
}

// global -> LDS async copy, 16B per lane; LDS fills base + lane*16.
__device__ __forceinline__ void gload_lds16(const void* g, void* l) {
    auto* gp = reinterpret_cast<const __attribute__((address_space(1))) uint32_t*>(
        reinterpret_cast<uintptr_t>(g));
    auto* lp = reinterpret_cast<__attribute__((address_space(3))) uint32_t*>(
        reinterpret_cast<uintptr_t>(l));
    __builtin_amdgcn_global_load_lds(gp, lp, 16, 0, 0);
}

// ---------------------------------------------------------------------------
// bf16 MFMA GEMM, 128x128 tile, 4 waves, double-buffered K-loop.
// C = A[M,K] @ Bt[N,K]^T. Epilogue: +bias, relu, bf16 out (pitch ldc).
// Used for FFN1 (grid (16,128) = 2048 blocks).
// ---------------------------------------------------------------------------
__global__ __launch_bounds__(256) void gemm_bt(
    const __hip_bfloat16* __restrict__ A, int lda,
    const __hip_bfloat16* __restrict__ Bt, int ldb,
    const float* __restrict__ bias,
    __hip_bfloat16* __restrict__ outb, int ldc,
    int M, int N, int K, int relu)
{
    __shared__ short Asm[2][128 * 32];
    __shared__ short Bsm[2][128 * 32];

    const int tid  = threadIdx.x;
    const int lane = tid & 63;
    const int wid  = tid >> 6;
    const int wr   = wid >> 1;
    const int wc   = wid & 1;
    const int bm   = blockIdx.y * 128;
    const int bn   = blockIdx.x * 128;

    f32x4 acc[4][4] = {};
    const int srow = lane >> 2;
    const int seg  = (lane & 3) * 8;

    auto stage = [&](int buf, int k0) {
        #pragma unroll
        for (int t = 0; t < 2; ++t) {
            int rbase = wid * 32 + t * 16;
            gload_lds16(A  + (size_t)(bm + rbase + srow) * lda + k0 + seg, &Asm[buf][rbase * 32]);
            gload_lds16(Bt + (size_t)(bn + rbase + srow) * ldb + k0 + seg, &Bsm[buf][rbase * 32]);
        }
    };

    const int nk = K >> 5;
    stage(0, 0);
    __syncthreads();

    for (int kk = 0; kk < nk; ++kk) {
        const int cur = kk & 1;
        if (kk + 1 < nk) stage(cur ^ 1, (kk + 1) << 5);

        bf16x8 a[4], b[4];
        #pragma unroll
        for (int i = 0; i < 4; ++i)
            a[i] = *(const bf16x8*)&Asm[cur][(wr * 64 + i * 16 + (lane & 15)) * 32 + (lane >> 4) * 8];
        #pragma unroll
        for (int j = 0; j < 4; ++j)
            b[j] = *(const bf16x8*)&Bsm[cur][(wc * 64 + j * 16 + (lane & 15)) * 32 + (lane >> 4) * 8];
        #pragma unroll
        for (int i = 0; i < 4; ++i)
            #pragma unroll
            for (int j = 0; j < 4; ++j)
                acc[i][j] = __builtin_amdgcn_mfma_f32_16x16x32_bf16(a[i], b[j], acc[i][j], 0, 0, 0);
        __syncthreads();
    }

    #pragma unroll
    for (int i = 0; i < 4; ++i) {
        int rbase = bm + wr * 64 + i * 16 + ((lane >> 4) << 2);
        #pragma unroll
        for (int j = 0; j < 4; ++j) {
            int col = bn + wc * 64 + j * 16 + (lane & 15);
            float bval = bias ? bias[col] : 0.0f;
            #pragma unroll
            for (int r = 0; r < 4; ++r) {
                int row = rbase + r;
                float v = acc[i][j][r] + bval;
                if (relu) v = fmaxf(v, 0.0f);
                outb[(size_t)row * ldc + col] = __float2bfloat16(v);
            }
        }
    }
}

// ---------------------------------------------------------------------------
// BK=64 LN-GEMM: BM=64 x N=256, 8 waves (2x4), wave = 32x64.
// 16 MFMA + 12 ds_read_b128 per barrier pair (m97 density) vs ln8's 8+6.
// Double-buffered via DYNAMIC LDS (86.5 KB). Staging XOR-swizzled both sides
// (source chunk ^= row&7, read chunk ^= row&7) -> ~conflict-free b128 reads.
// Fused bias + residual + LayerNorm epilogue. Grid = M/64 = 256 blocks.
// ---------------------------------------------------------------------------
__global__ __launch_bounds__(512) void gemm_bk64_ln(
    const __hip_bfloat16* __restrict__ A, int lda,
    const __hip_bfloat16* __restrict__ Bt, int ldb,
    const float* __restrict__ bias,
    const float* __restrict__ residf,
    const __hip_bfloat16* __restrict__ residb,
    const float* __restrict__ g,
    const float* __restrict__ be,
    float* __restrict__ outf,
    __hip_bfloat16* __restrict__ outb,
    int K)
{
    extern __shared__ char smem[];
    short* AsmB = (short*)smem;                      // [2][64*64]   16 KB
    short* BsmB = (short*)(smem + 16384);            // [2][256*64]  64 KB
    float* lnS  = (float*)(smem + 81920);            // [8][64]
    float* lnS2 = (float*)(smem + 83968);            // [8][64]
    float* rmu  = (float*)(smem + 86016);            // [64]
    float* rrs  = (float*)(smem + 86272);            // [64]

    const int tid  = threadIdx.x;
    const int lane = tid & 63;
    const int wid  = tid >> 6;           // 0..7
    const int wr   = wid >> 2;           // 0..1 (32-row half)
    const int wc   = wid & 3;            // 0..3 (64-col quarter)
    const int bm   = blockIdx.x * 64;
    const int lo   = lane & 15;
    const int hi   = lane >> 4;

    f32x4 acc[2][4] = {};

    // staging lane decomposition: stripe = 8 rows x 8 chunks (16B each)
    const int srow8 = lane >> 3;         // row within stripe
    const int sc    = lane & 7;          // chunk slot
    const int ssw   = ((sc ^ srow8) << 3);   // swizzled source chunk (elems)

    auto stage = [&](int buf, int k0) {
        // A: 8 stripes of 8 rows, one per wave
        gload_lds16(A + (size_t)(bm + wid * 8 + srow8) * lda + k0 + ssw,
                    AsmB + buf * 4096 + (wid * 8) * 64);
        // B: 32 stripes, 4 per wave
        #pragma unroll
        for (int t = 0; t < 4; ++t) {
            int rb = wid * 32 + t * 8;
            gload_lds16(Bt + (size_t)(rb + srow8) * ldb + k0 + ssw,
                        BsmB + buf * 16384 + rb * 64);
        }
    };

    const int nk = K >> 6;
    stage(0, 0);
    __syncthreads();

    for (int kk = 0; kk < nk; ++kk) {
        const int cur = kk & 1;
        if (kk + 1 < nk) stage(cur ^ 1, (kk + 1) << 6);

        const short* Ab = AsmB + cur * 4096;
        const short* Bb = BsmB + cur * 16384;
        #pragma unroll
        for (int ks = 0; ks < 2; ++ks) {
            const int csw = ((ks * 4 + hi) ^ (lo & 7)) << 3;  // swizzled read chunk
            bf16x8 a[2], b[4];
            #pragma unroll
            for (int i = 0; i < 2; ++i)
                a[i] = *(const bf16x8*)&Ab[(wr * 32 + i * 16 + lo) * 64 + csw];
            #pragma unroll
            for (int j = 0; j < 4; ++j)
                b[j] = *(const bf16x8*)&Bb[(wc * 64 + j * 16 + lo) * 64 + csw];
            #pragma unroll
            for (int i = 0; i < 2; ++i)
                #pragma unroll
                for (int j = 0; j < 4; ++j)
                    acc[i][j] = __builtin_amdgcn_mfma_f32_16x16x32_bf16(a[i], b[j], acc[i][j], 0, 0, 0);
        }
        __syncthreads();
    }

    // epilogue: bias + resid, per-row mean/var partials over this wave's 64 cols
    float ps[2][4] = {}, ps2[2][4] = {};
    #pragma unroll
    for (int j = 0; j < 4; ++j) {
        int col = wc * 64 + j * 16 + lo;
        float bval = bias ? bias[col] : 0.0f;
        #pragma unroll
        for (int i = 0; i < 2; ++i) {
            #pragma unroll
            for (int r = 0; r < 4; ++r) {
                int row = bm + wr * 32 + i * 16 + hi * 4 + r;
                float v = acc[i][j][r] + bval;
                size_t o = (size_t)row * 256 + col;
                if (residf) v += residf[o];
                if (residb) v += __bfloat162float(residb[o]);
                acc[i][j][r] = v;
                ps[i][r]  += v;
                ps2[i][r] += v * v;
            }
        }
    }
    #pragma unroll
    for (int i = 0; i < 2; ++i)
        #pragma unroll
        for (int r = 0; r < 4; ++r) {
            #pragma unroll
            for (int m = 1; m < 16; m <<= 1) {
                ps[i][r]  += __shfl_xor(ps[i][r],  m);
                ps2[i][r] += __shfl_xor(ps2[i][r], m);
            }
        }
    if (lo == 0) {
        #pragma unroll
        for (int i = 0; i < 2; ++i)
            #pragma unroll
            for (int r = 0; r < 4; ++r) {
                int rl = wr * 32 + i * 16 + hi * 4 + r;
                lnS[wid * 64 + rl]  = ps[i][r];
                lnS2[wid * 64 + rl] = ps2[i][r];
            }
    }
    __syncthreads();
    if (tid < 64) {
        int base = (tid >> 5) * 4;       // the 4 waves (wc=0..3) sharing this row
        float s  = lnS[base * 64 + tid] + lnS[(base + 1) * 64 + tid]
                 + lnS[(base + 2) * 64 + tid] + lnS[(base + 3) * 64 + tid];
        float s2 = lnS2[base * 64 + tid] + lnS2[(base + 1) * 64 + tid]
                 + lnS2[(base + 2) * 64 + tid] + lnS2[(base + 3) * 64 + tid];
        float mu  = s * (1.0f / 256.0f);
        float var = s2 * (1.0f / 256.0f) - mu * mu;
        rmu[tid] = mu;
        rrs[tid] = rsqrtf(var + 1e-5f);
    }
    __syncthreads();

    #pragma unroll
    for (int j = 0; j < 4; ++j) {
        int col = wc * 64 + j * 16 + lo;
        float gg = g[col], bb = be[col];
        #pragma unroll
        for (int i = 0; i < 2; ++i) {
            #pragma unroll
            for (int r = 0; r < 4; ++r) {
                int rl = wr * 32 + i * 16 + hi * 4 + r;
                float v = (acc[i][j][r] - rmu[rl]) * rrs[rl] * gg + bb;
                size_t o = (size_t)(bm + rl) * 256 + col;
                if (outf) outf[o] = v;
                if (outb) outb[o] = __float2bfloat16(v);
            }
        }
    }
}

// ---------------------------------------------------------------------------
// QKV GEMM: C = src_bf @ WqkvT^T (N=768, K=256), split epilogue:
// cols [0,256)  -> qf  f32 [N_TOK][256]   (scale pre-folded)
// cols [256,768)-> kvb bf16 [N_TOK][512]  (k|v, gather-friendly, L2-resident)
// ---------------------------------------------------------------------------
__global__ __launch_bounds__(256) void gemm_qkv(
    const __hip_bfloat16* __restrict__ A,
    const __hip_bfloat16* __restrict__ Bt,
    const float* __restrict__ bias,
    float* __restrict__ qf,
    __hip_bfloat16* __restrict__ kvb)
{
    __shared__ short Asm[2][128 * 32];
    __shared__ short Bsm[2][128 * 32];

    const int tid  = threadIdx.x;
    const int lane = tid & 63;
    const int wid  = tid >> 6;
    const int wr   = wid >> 1;
    const int wc   = wid & 1;
    const int bm   = blockIdx.y * 128;
    const int bn   = blockIdx.x * 128;

    f32x4 acc[4][4] = {};
    const int srow = lane >> 2;
    const int seg  = (lane & 3) * 8;

    auto stage = [&](int buf, int k0) {
        #pragma unroll
        for (int t = 0; t < 2; ++t) {
            int rbase = wid * 32 + t * 16;
            gload_lds16(A  + (size_t)(bm + rbase + srow) * 256 + k0 + seg, &Asm[buf][rbase * 32]);
            gload_lds16(Bt + (size_t)(bn + rbase + srow) * 256 + k0 + seg, &Bsm[buf][rbase * 32]);
        }
    };

    stage(0, 0);
    __syncthreads();
    for (int kk = 0; kk < 8; ++kk) {
        const int cur = kk & 1;
        if (kk + 1 < 8) stage(cur ^ 1, (kk + 1) << 5);
        bf16x8 a[4], b[4];
        #pragma unroll
        for (int i = 0; i < 4; ++i)
            a[i] = *(const bf16x8*)&Asm[cur][(wr * 64 + i * 16 + (lane & 15)) * 32 + (lane >> 4) * 8];
        #pragma unroll
        for (int j = 0; j < 4; ++j)
            b[j] = *(const bf16x8*)&Bsm[cur][(wc * 64 + j * 16 + (lane & 15)) * 32 + (lane >> 4) * 8];
        #pragma unroll
        for (int i = 0; i < 4; ++i)
            #pragma unroll
            for (int j = 0; j < 4; ++j)
                acc[i][j] = __builtin_amdgcn_mfma_f32_16x16x32_bf16(a[i], b[j], acc[i][j], 0, 0, 0);
        __syncthreads();
    }

    const bool isq = (bn < 256);
    #pragma unroll
    for (int i = 0; i < 4; ++i) {
        int rbase = bm + wr * 64 + i * 16 + ((lane >> 4) << 2);
        #pragma unroll
        for (int j = 0; j < 4; ++j) {
            int col = bn + wc * 64 + j * 16 + (lane & 15);
            float bval = bias[col];
            #pragma unroll
            for (int r = 0; r < 4; ++r) {
                int row = rbase + r;
                float v = acc[i][j][r] + bval;
                if (isq) qf[(size_t)row * 256 + col] = v;
                else     kvb[(size_t)row * 512 + (col - 256)] = __float2bfloat16(v);
            }
        }
    }
}

// ---------------------------------------------------------------------------
__global__ __launch_bounds__(256) void cvt_f2b(
    const float* __restrict__ x, __hip_bfloat16* __restrict__ y, int n)
{
    int i = (blockIdx.x * 256 + threadIdx.x) * 4;
    if (i >= n) return;
    float4 v = *(const float4*)(x + i);
    y[i + 0] = __float2bfloat16(v.x);
    y[i + 1] = __float2bfloat16(v.y);
    y[i + 2] = __float2bfloat16(v.z);
    y[i + 3] = __float2bfloat16(v.w);
}

// Tiled transpose: W[K][N] fp32 -> Wt[N][K] bf16, output pitch ldo.
__global__ __launch_bounds__(256) void cvt_wt_tiled(
    const float* __restrict__ W, __hip_bfloat16* __restrict__ Wt,
    int K, int N, int ldo, float scale)
{
    __shared__ float t[32][33];
    const int n0 = blockIdx.x * 32;
    const int k0 = blockIdx.y * 32;
    const int tx = threadIdx.x & 31;
    const int ty = threadIdx.x >> 5;
    #pragma unroll
    for (int i = 0; i < 32; i += 8)
        t[ty + i][tx] = W[(size_t)(k0 + ty + i) * N + n0 + tx];
    __syncthreads();
    #pragma unroll
    for (int i = 0; i < 32; i += 8)
        Wt[(size_t)(n0 + ty + i) * ldo + k0 + tx] = __float2bfloat16(t[tx][ty + i] * scale);
}

__global__ __launch_bounds__(256) void cvt_w3_tiled(
    const float* __restrict__ Wa, const float* __restrict__ Wb,
    const float* __restrict__ Wc, __hip_bfloat16* __restrict__ Wt,
    float scale_a)
{
    __shared__ float t[32][33];
    const int n0 = blockIdx.x * 32;
    const int k0 = blockIdx.y * 32;
    const float* W = (n0 < 256) ? Wa : (n0 < 512 ? Wb : Wc);
    const float sc = (n0 < 256) ? scale_a : 1.0f;
    const int ncol = n0 & 255;
    const int tx = threadIdx.x & 31;
    const int ty = threadIdx.x >> 5;
    #pragma unroll
    for (int i = 0; i < 32; i += 8)
        t[ty + i][tx] = W[(size_t)(k0 + ty + i) * 256 + ncol + tx];
    __syncthreads();
    #pragma unroll
    for (int i = 0; i < 32; i += 8)
        Wt[(size_t)(n0 + ty + i) * 256 + k0 + tx] = __float2bfloat16(t[tx][ty + i] * sc);
}

// biases + key_start prefix sums (batch offsets)
__global__ __launch_bounds__(768) void make_bqkv(
    const float* __restrict__ bq, const float* __restrict__ bk,
    const float* __restrict__ bv, const int* __restrict__ kbc, int nb,
    float* __restrict__ o, int* __restrict__ ks, float qs)
{
    int i = threadIdx.x;
    if (i < 256)      o[i] = bq[i] * qs;
    else if (i < 512) o[i] = bk[i - 256];
    else              o[i] = bv[i - 512];
    if (i < nb) {
        int acc = 0;
        for (int j = 0; j < i; ++j) acc += kbc[j];
        ks[i] = acc;
    }
}

// ---------------------------------------------------------------------------
// Gathered local attention: ONE WAVE per query, fully coalesced row gathers.
// (unchanged from round 9 — 210->169 us win)
// ---------------------------------------------------------------------------
__global__ __launch_bounds__(256) void attn_wave(
    const float* __restrict__ qf,
    const __hip_bfloat16* __restrict__ kvb,
    const int* __restrict__ index_pair,
    const int* __restrict__ ipb,
    const int* __restrict__ key_start,
    __hip_bfloat16* __restrict__ out)
{
    const int w    = threadIdx.x >> 6;
    const int lane = threadIdx.x & 63;
    const int bid  = blockIdx.x;
    const int n  = (bid & 7) * 2048 + (bid >> 3) * 4 + w;
    const int c  = lane & 31;      // dim chunk: dims [c*8, c*8+8)
    const int pp = lane >> 5;      // row parity

    int raw = index_pair[(size_t)n * LNEIGH + c];
    int ks  = key_start[ipb[n]];
    int gi0 = (raw >= 0) ? raw + ks : -1;

    const float* qp = qf + (size_t)n * 256 + c * 8;
    float4 q0 = *(const float4*)(qp);
    float4 q1 = *(const float4*)(qp + 4);

    int gi[16];
    #pragma unroll
    for (int i = 0; i < 16; ++i) gi[i] = __shfl(gi0, 2 * i + pp);

    bf16x8 kr[16];
    #pragma unroll
    for (int i = 0; i < 16; ++i) {
        int g = gi[i] < 0 ? 0 : gi[i];
        kr[i] = *(const bf16x8*)(kvb + (size_t)g * 512 + c * 8);
    }

    float s[16];
    #pragma unroll
    for (int i = 0; i < 16; ++i) {
        float t = q0.x * b2f(kr[i][0]) + q0.y * b2f(kr[i][1])
                + q0.z * b2f(kr[i][2]) + q0.w * b2f(kr[i][3])
                + q1.x * b2f(kr[i][4]) + q1.y * b2f(kr[i][5])
                + q1.z * b2f(kr[i][6]) + q1.w * b2f(kr[i][7]);
        t += __shfl_xor(t, 1);
        t += __shfl_xor(t, 2);
        s[i] = (gi[i] < 0) ? -1e9f : t;
    }

    bf16x8 vr[16];
    #pragma unroll
    for (int i = 0; i < 16; ++i) {
        int g = gi[i] < 0 ? 0 : gi[i];
        vr[i] = *(const bf16x8*)(kvb + (size_t)g * 512 + 256 + c * 8);
    }

    float m = s[0];
    #pragma unroll
    for (int i = 1; i < 16; ++i) m = fmaxf(m, s[i]);
    m = fmaxf(m, __shfl_xor(m, 32));
    float tot = 0.0f;
    #pragma unroll
    for (int i = 0; i < 16; ++i) { s[i] = __expf(s[i] - m); tot += s[i]; }
    tot += __shfl_xor(tot, 32);
    const float inv = 1.0f / tot;

    float a[8] = {};
    #pragma unroll
    for (int i = 0; i < 16; ++i) {
        float wt = s[i] * inv;
        #pragma unroll
        for (int j = 0; j < 8; ++j) a[j] += wt * b2f(vr[i][j]);
    }
    #pragma unroll
    for (int j = 0; j < 8; ++j) a[j] += __shfl_xor(a[j], 32);

    if (pp == 0) {
        bf16x8 ov;
        #pragma unroll
        for (int j = 0; j < 8; ++j)
            ov[j] = __builtin_bit_cast(short, __float2bfloat16(a[j]));
        *(bf16x8*)((short*)out + (size_t)n * 256 + c * 8) = ov;
    }
}

// ---------------------------------------------------------------------------
extern "C" void kernel_launch(void* const* d_in, const int* in_sizes, int n_in,
                              void* d_out, int out_size, void* d_ws, size_t ws_size,
                              hipStream_t stream)
{
    const float* src = (const float*)d_in[0];
    const int*   index_pair = (const int*)d_in[1];
    const int*   kbc = (const int*)d_in[3];
    const int*   ipb = (const int*)d_in[4];
    const float* Wq = (const float*)d_in[5];
    const float* bq = (const float*)d_in[6];
    const float* Wk = (const float*)d_in[7];
    const float* bk = (const float*)d_in[8];
    const float* Wv = (const float*)d_in[9];
    const float* bv = (const float*)d_in[10];
    const float* Wo = (const float*)d_in[11];
    const float* bo = (const float*)d_in[12];
    const float* W1 = (const float*)d_in[13];
    const float* b1 = (const float*)d_in[14];
    const float* W2 = (const float*)d_in[15];
    const float* b2 = (const float*)d_in[16];
    const float* g1 = (const float*)d_in[17];
    const float* be1 = (const float*)d_in[18];
    const float* g2 = (const float*)d_in[19];
    const float* be2 = (const float*)d_in[20];
    float* out = (float*)d_out;
    const int nb = in_sizes[3];   // number of batches

    char* ws = (char*)d_ws;
    // Attention-phase buffers die before FFN1; hc (64 MB at offset 0) aliases.
    const size_t O_SRCBF = 0;                        //  8.39 MB bf16 src
    const size_t O_QF    = 8388608;                  // 16.78 MB f32 q
    const size_t O_KVB   = 25165824;                 // 16.78 MB bf16 k|v
    const size_t O_ATTN  = 41943040;                 //  8.39 MB bf16 attn out
    const size_t O_HC    = 0;                        // 64 MB alias (FFN hidden)
    const size_t O_XBF   = 67108864;                 //  8.39 MB bf16 x (LN1 out)
    const size_t O_WQKV  = 75497472;
    const size_t O_WO    = O_WQKV + 768 * 256 * 2;
    const size_t O_W1    = O_WO + 256 * 256 * 2;
    const size_t O_W2    = O_W1 + (size_t)DFF * 256 * 2;
    const size_t O_BQKV  = O_W2 + (size_t)DFF * 256 * 2;
    const size_t O_KS    = O_BQKV + 768 * 4;

    __hip_bfloat16* src_bf  = (__hip_bfloat16*)(ws + O_SRCBF);
    float*          qf      = (float*)(ws + O_QF);
    __hip_bfloat16* kvb     = (__hip_bfloat16*)(ws + O_KVB);
    __hip_bfloat16* attn_bf = (__hip_bfloat16*)(ws + O_ATTN);
    __hip_bfloat16* hc      = (__hip_bfloat16*)(ws + O_HC);
    __hip_bfloat16* x_bf    = (__hip_bfloat16*)(ws + O_XBF);
    __hip_bfloat16* WqkvT   = (__hip_bfloat16*)(ws + O_WQKV);
    __hip_bfloat16* WoT     = (__hip_bfloat16*)(ws + O_WO);
    __hip_bfloat16* W1T     = (__hip_bfloat16*)(ws + O_W1);
    __hip_bfloat16* W2T     = (__hip_bfloat16*)(ws + O_W2);
    float*          bqkv    = (float*)(ws + O_BQKV);
    int*            ksbuf   = (int*)(ws + O_KS);

    const dim3 blk(256);
    const float qscale = 0.17677669529663687f;

    // allow the BK=64 LN-GEMM its 86.5 KB of dynamic LDS
    hipFuncSetAttribute(reinterpret_cast<const void*>(gemm_bk64_ln),
                        hipFuncAttributeMaxDynamicSharedMemorySize, SMEM_LN);

    // --- conversions ---
    cvt_f2b<<<N_TOK * D_MODEL / 4 / 256, blk, 0, stream>>>(src, src_bf, N_TOK * D_MODEL);
    cvt_w3_tiled<<<dim3(24, 8), blk, 0, stream>>>(Wq, Wk, Wv, WqkvT, qscale);
    cvt_wt_tiled<<<dim3(8, 8),  blk, 0, stream>>>(Wo, WoT, 256, 256, 256, 1.0f);
    cvt_wt_tiled<<<dim3(64, 8), blk, 0, stream>>>(W1, W1T, 256, DFF, 256, 1.0f);
    cvt_wt_tiled<<<dim3(8, 64), blk, 0, stream>>>(W2, W2T, DFF, 256, DFF, 1.0f);
    make_bqkv<<<1, 768, 0, stream>>>(bq, bk, bv, kbc, nb, bqkv, ksbuf, qscale);

    // --- fused QKV projection: q -> f32 qf, k|v -> bf16 kvb ---
    gemm_qkv<<<dim3(6, 128), blk, 0, stream>>>(src_bf, WqkvT, bqkv, qf, kvb);

    // --- gathered attention (wave per query, coalesced row gathers) ---
    attn_wave<<<dim3(N_TOK / 4), blk, 0, stream>>>(qf, kvb, index_pair, ipb, ksbuf, attn_bf);

    // --- Wo + residual(src) + LN1 fused -> x_bf (BK=64 LN-GEMM) ---
    gemm_bk64_ln<<<dim3(N_TOK / 64), dim3(512), SMEM_LN, stream>>>(
        attn_bf, 256, WoT, 256, bo, src, nullptr, g1, be1,
        nullptr, x_bf, 256);

    // --- FFN1 (N=2048, relu) -> hc ---
    gemm_bt<<<dim3(16, 128), blk, 0, stream>>>(
        x_bf, 256, W1T, 256, b1, hc, DFF, N_TOK, DFF, 256, 1);

    // --- FFN2 + residual(x_bf) + LN2 fused -> out (BK=64 LN-GEMM) ---
    gemm_bk64_ln<<<dim3(N_TOK / 64), dim3(512), SMEM_LN, stream>>>(
        hc, DFF, W2T, DFF, b2, nullptr, x_bf, g2, be2,
        out, nullptr, DFF);
}